// Round 1
// baseline (1145.862 us; speedup 1.0000x reference)
//
#include <hip/hip_runtime.h>
#include <hip/hip_bf16.h>
#include <cstdint>

#define B_ 64
#define T_ 1024
#define I_ 128
#define H_ 512
#define O_ 512

typedef short bf16x8 __attribute__((ext_vector_type(8)));
typedef float f32x4 __attribute__((ext_vector_type(4)));

typedef const __attribute__((address_space(1))) void* gptr_t;
typedef __attribute__((address_space(3))) void* lptr_t;

__device__ __forceinline__ unsigned short f2bf(float f) {
    unsigned int u = __float_as_uint(f);
    u += 0x7fffu + ((u >> 16) & 1u);   // RNE
    return (unsigned short)(u >> 16);
}
__device__ __forceinline__ float bf2f(unsigned short b) {
    return __uint_as_float(((unsigned int)b) << 16);
}
__device__ __forceinline__ float fast_tanh(float x) {
    // tanh(x) = 1 - 2/(exp(2x)+1); exp(2x) = 2^(x * 2/ln2)
    float e = __builtin_amdgcn_exp2f(x * 2.8853900817779268f);
    return 1.0f - 2.0f * __builtin_amdgcn_rcpf(e + 1.0f);
}

// ---------------------------------------------------------------- cast fp32->bf16
__global__ __launch_bounds__(256)
void cast_f32_bf16(const float* __restrict__ s, unsigned short* __restrict__ d, int n) {
    int i = (blockIdx.x * 256 + threadIdx.x) * 4;
    if (i >= n) return;
    float4 v = *(const float4*)(s + i);
    ushort4 o;
    o.x = f2bf(v.x); o.y = f2bf(v.y); o.z = f2bf(v.z); o.w = f2bf(v.w);
    *(ushort4*)(d + i) = o;
}

// ---------------------------------------------------------------- GEMM  C[M,N] = A[M,K] * B[N,K]^T + bias
// m97 structure: 128x128 tile, BK=32, 4 waves (2x2) of 64x64 each, 16x16x32 bf16 MFMA,
// global_load_lds width=16 staging into unpadded row-major LDS [128][32].
template <bool STORE_BF16>
__global__ __launch_bounds__(256)
void gemm_bt(const unsigned short* __restrict__ A,   // [M,K] bf16 bits
             const unsigned short* __restrict__ Bm,  // [N,K] bf16 bits
             const float* __restrict__ bias,         // [N]
             void* __restrict__ Cout,                // [M,N]
             int M, int N, int K) {
    __shared__ unsigned short As[128 * 32];
    __shared__ unsigned short Bs[128 * 32];

    const int tid  = threadIdx.x;
    const int lane = tid & 63;
    const int w    = tid >> 6;            // wave 0..3 (uniform per wave)
    const int wm   = (w >> 1) * 64;
    const int wn   = (w & 1) * 64;
    const int nblk = N >> 7;
    const int bm   = (int)(blockIdx.x / nblk) << 7;
    const int bn   = (int)(blockIdx.x % nblk) << 7;

    f32x4 acc[4][4] = {};

    // staging: thread t covers row t/4 (issue adds +64), cols (t%4)*8 .. +8
    const int srow = tid >> 2;
    const int scol = (tid & 3) << 3;
    const unsigned short* gA0 = A  + (size_t)(bm + srow) * K + scol;
    const unsigned short* gA1 = A  + (size_t)(bm + 64 + srow) * K + scol;
    const unsigned short* gB0 = Bm + (size_t)(bn + srow) * K + scol;
    const unsigned short* gB1 = Bm + (size_t)(bn + 64 + srow) * K + scol;

    // wave-uniform LDS bases: thread t writes byte t*16 (+issue*4096); base = w*1024 bytes
    unsigned short* ldsA0 = As + w * 512;
    unsigned short* ldsA1 = As + 2048 + w * 512;
    unsigned short* ldsB0 = Bs + w * 512;
    unsigned short* ldsB1 = Bs + 2048 + w * 512;

    const int frow = lane & 15;          // m (or n) within 16-tile
    const int fk   = (lane >> 4) << 3;   // k offset (quad*8)

    for (int kt = 0; kt < K; kt += 32) {
        __syncthreads();
        __builtin_amdgcn_global_load_lds((gptr_t)(gA0 + kt), (lptr_t)ldsA0, 16, 0, 0);
        __builtin_amdgcn_global_load_lds((gptr_t)(gA1 + kt), (lptr_t)ldsA1, 16, 0, 0);
        __builtin_amdgcn_global_load_lds((gptr_t)(gB0 + kt), (lptr_t)ldsB0, 16, 0, 0);
        __builtin_amdgcn_global_load_lds((gptr_t)(gB1 + kt), (lptr_t)ldsB1, 16, 0, 0);
        __syncthreads();

        bf16x8 af[4], bf[4];
#pragma unroll
        for (int mt = 0; mt < 4; ++mt)
            af[mt] = *(const bf16x8*)(As + (wm + mt * 16 + frow) * 32 + fk);
#pragma unroll
        for (int nt = 0; nt < 4; ++nt)
            bf[nt] = *(const bf16x8*)(Bs + (wn + nt * 16 + frow) * 32 + fk);
#pragma unroll
        for (int mt = 0; mt < 4; ++mt)
#pragma unroll
            for (int nt = 0; nt < 4; ++nt)
                acc[mt][nt] = __builtin_amdgcn_mfma_f32_16x16x32_bf16(
                    af[mt], bf[nt], acc[mt][nt], 0, 0, 0);
    }

    // epilogue: C/D layout col = lane&15, row = (lane>>4)*4 + reg  [m89-verified]
    const int c_col = lane & 15;
    const int c_row = (lane >> 4) << 2;
#pragma unroll
    for (int nt = 0; nt < 4; ++nt) {
        const int gn = bn + wn + nt * 16 + c_col;
        const float bv = bias[gn];
#pragma unroll
        for (int mt = 0; mt < 4; ++mt) {
            const int gm0 = bm + wm + mt * 16 + c_row;
#pragma unroll
            for (int r = 0; r < 4; ++r) {
                float v = acc[mt][nt][r] + bv;
                size_t idx = (size_t)(gm0 + r) * N + gn;
                if (STORE_BF16) ((unsigned short*)Cout)[idx] = f2bf(v);
                else            ((float*)Cout)[idx] = v;
            }
        }
    }
}

// ---------------------------------------------------------------- sequential scan
// 1 wave per batch element. Lane owns h[lane*8 .. lane*8+7] in registers.
__global__ __launch_bounds__(64)
void scan_kernel(const unsigned short* __restrict__ xproj,  // (B,T,H) bf16
                 const float* __restrict__ h0,              // (B,H)
                 const float* __restrict__ U,               // (H,2)
                 const float* __restrict__ V,               // (H,2)
                 float* __restrict__ hall_f32,              // (B,T,H) -> d_out
                 unsigned short* __restrict__ hall_bf) {    // (B,T,H) -> ws
    const int b = blockIdx.x;
    const int lane = threadIdx.x;
    const int hbase = lane * 8;

    float h[8], V0[8], V1[8], U0[8], U1[8];
#pragma unroll
    for (int j = 0; j < 8; ++j) {
        h[j]  = h0[b * H_ + hbase + j];
        V0[j] = V[(hbase + j) * 2 + 0];
        V1[j] = V[(hbase + j) * 2 + 1];
        U0[j] = U[(hbase + j) * 2 + 0];
        U1[j] = U[(hbase + j) * 2 + 1];
    }

    const unsigned short* xp_ptr = xproj + (size_t)b * T_ * H_ + hbase;
    float* ho = hall_f32 + (size_t)b * T_ * H_ + hbase;
    unsigned short* hb = hall_bf + (size_t)b * T_ * H_ + hbase;

    const float inv_h = 1.0f / (float)H_;
    uint4 xcur = *(const uint4*)xp_ptr;

    for (int t = 0; t < T_; ++t) {
        uint4 xnext = make_uint4(0u, 0u, 0u, 0u);
        if (t + 1 < T_) xnext = *(const uint4*)(xp_ptr + (size_t)(t + 1) * H_);

        // partial dots over this lane's 8 elements
        float s0 = 0.f, s1 = 0.f;
#pragma unroll
        for (int j = 0; j < 8; ++j) { s0 += h[j] * V0[j]; s1 += h[j] * V1[j]; }
        // wave-wide reduction (64 lanes)
#pragma unroll
        for (int off = 32; off > 0; off >>= 1) {
            s0 += __shfl_xor(s0, off, 64);
            s1 += __shfl_xor(s1, off, 64);
        }

        // unpack xproj (bf16) for this step
        float xp[8];
        {
            unsigned int uu[4] = {xcur.x, xcur.y, xcur.z, xcur.w};
#pragma unroll
            for (int q = 0; q < 4; ++q) {
                xp[2 * q + 0] = bf2f((unsigned short)(uu[q] & 0xffffu));
                xp[2 * q + 1] = bf2f((unsigned short)(uu[q] >> 16));
            }
        }

#pragma unroll
        for (int j = 0; j < 8; ++j) {
            float pre = xp[j] + (s0 * U0[j] + s1 * U1[j]) * inv_h;
            h[j] = 0.9f * h[j] + 0.1f * fast_tanh(pre);
        }

        // store fp32 h_all (d_out) and bf16 copy (ws) for phase-3 GEMM
        float4 v0 = make_float4(h[0], h[1], h[2], h[3]);
        float4 v1 = make_float4(h[4], h[5], h[6], h[7]);
        *(float4*)(ho + (size_t)t * H_ + 0) = v0;
        *(float4*)(ho + (size_t)t * H_ + 4) = v1;
        uint4 pb;
        pb.x = ((unsigned int)f2bf(h[1]) << 16) | f2bf(h[0]);
        pb.y = ((unsigned int)f2bf(h[3]) << 16) | f2bf(h[2]);
        pb.z = ((unsigned int)f2bf(h[5]) << 16) | f2bf(h[4]);
        pb.w = ((unsigned int)f2bf(h[7]) << 16) | f2bf(h[6]);
        *(uint4*)(hb + (size_t)t * H_) = pb;

        xcur = xnext;
    }
}

// ---------------------------------------------------------------- launch
extern "C" void kernel_launch(void* const* d_in, const int* in_sizes, int n_in,
                              void* d_out, int out_size, void* d_ws, size_t ws_size,
                              hipStream_t stream) {
    const float* x   = (const float*)d_in[0];
    const float* h0  = (const float*)d_in[1];
    const float* Wxh = (const float*)d_in[2];
    const float* bxh = (const float*)d_in[3];
    const float* U   = (const float*)d_in[4];
    const float* V   = (const float*)d_in[5];
    const float* Why = (const float*)d_in[6];
    const float* bhy = (const float*)d_in[7];

    float* y    = (float*)d_out;                    // (B,T,O)
    float* hall = y + (size_t)B_ * T_ * O_;         // (B,T,H)

    // workspace layout (bf16 buffers), total ~151.7 MB
    unsigned short* x_bf    = (unsigned short*)d_ws;                 // B*T*I
    unsigned short* Wxh_bf  = x_bf + (size_t)B_ * T_ * I_;           // H*I
    unsigned short* Why_bf  = Wxh_bf + (size_t)H_ * I_;              // O*H
    unsigned short* xp_bf   = Why_bf + (size_t)O_ * H_;              // B*T*H
    unsigned short* hall_bf = xp_bf + (size_t)B_ * T_ * H_;          // B*T*H

    // casts
    cast_f32_bf16<<<(B_ * T_ * I_) / 1024, 256, 0, stream>>>(x, x_bf, B_ * T_ * I_);
    cast_f32_bf16<<<(H_ * I_) / 1024, 256, 0, stream>>>(Wxh, Wxh_bf, H_ * I_);
    cast_f32_bf16<<<(O_ * H_) / 1024, 256, 0, stream>>>(Why, Why_bf, O_ * H_);

    // phase 1: xproj = x @ Wxh^T + bxh  -> bf16
    gemm_bt<true><<<dim3((B_ * T_ / 128) * (H_ / 128)), 256, 0, stream>>>(
        x_bf, Wxh_bf, bxh, xp_bf, B_ * T_, H_, I_);

    // phase 2: sequential scan over T
    scan_kernel<<<B_, 64, 0, stream>>>(xp_bf, h0, U, V, hall, hall_bf);

    // phase 3: y = h_all @ Why^T + bhy -> fp32
    gemm_bt<false><<<dim3((B_ * T_ / 128) * (O_ / 128)), 256, 0, stream>>>(
        hall_bf, Why_bf, bhy, y, B_ * T_, O_, H_);
}

// Round 3
// 921.899 us; speedup vs baseline: 1.2429x; 1.2429x over previous
//
#include <hip/hip_runtime.h>
#include <hip/hip_bf16.h>
#include <cstdint>

#define B_ 64
#define T_ 1024
#define I_ 128
#define H_ 512
#define O_ 512

typedef short bf16x8 __attribute__((ext_vector_type(8)));
typedef float f32x4 __attribute__((ext_vector_type(4)));

typedef const __attribute__((address_space(1))) void* gptr_t;
typedef __attribute__((address_space(3))) void* lptr_t;

__device__ __forceinline__ unsigned short f2bf(float f) {
    unsigned int u = __float_as_uint(f);
    u += 0x7fffu + ((u >> 16) & 1u);   // RNE
    return (unsigned short)(u >> 16);
}
__device__ __forceinline__ float bf2f(unsigned short b) {
    return __uint_as_float(((unsigned int)b) << 16);
}
__device__ __forceinline__ float fast_tanh(float x) {
    // tanh(x) = 1 - 2/(exp(2x)+1); exp(2x) = 2^(x * 2/ln2)
    float e = __builtin_amdgcn_exp2f(x * 2.8853900817779268f);
    return 1.0f - 2.0f * __builtin_amdgcn_rcpf(e + 1.0f);
}

// One DPP reduction hop: v += dpp_move(v, CTRL); bound_ctrl=true -> invalid lanes read 0.
template <int CTRL>
__device__ __forceinline__ float dpp_add(float v) {
    int t = __builtin_amdgcn_update_dpp(0, __float_as_int(v), CTRL, 0xf, 0xf, true);
    return v + __int_as_float(t);
}
// Full 64-lane sum, result wave-uniform (SGPR via readlane 63).
// row_shr:1,2,4,8 -> row sums accumulate into lane {15,31,47,63};
// row_bcast:15 -> lane31 += sum(0..15 row0), lane63 += ...;
// row_bcast:31 -> lane63 = total.
__device__ __forceinline__ float wave_sum64(float v) {
    v = dpp_add<0x111>(v);  // row_shr:1
    v = dpp_add<0x112>(v);  // row_shr:2
    v = dpp_add<0x114>(v);  // row_shr:4
    v = dpp_add<0x118>(v);  // row_shr:8
    v = dpp_add<0x142>(v);  // row_bcast:15
    v = dpp_add<0x143>(v);  // row_bcast:31
    return __uint_as_float(__builtin_amdgcn_readlane(__float_as_uint(v), 63));
}

// ---------------------------------------------------------------- cast fp32->bf16
__global__ __launch_bounds__(256)
void cast_f32_bf16(const float* __restrict__ s, unsigned short* __restrict__ d, int n) {
    int i = (blockIdx.x * 256 + threadIdx.x) * 4;
    if (i >= n) return;
    float4 v = *(const float4*)(s + i);
    ushort4 o;
    o.x = f2bf(v.x); o.y = f2bf(v.y); o.z = f2bf(v.z); o.w = f2bf(v.w);
    *(ushort4*)(d + i) = o;
}

// ---------------------------------------------------------------- GEMM  C[M,N] = A[M,K] * B[N,K]^T + bias
template <bool STORE_BF16>
__global__ __launch_bounds__(256)
void gemm_bt(const unsigned short* __restrict__ A,   // [M,K] bf16 bits
             const unsigned short* __restrict__ Bm,  // [N,K] bf16 bits
             const float* __restrict__ bias,         // [N]
             void* __restrict__ Cout,                // [M,N]
             int M, int N, int K) {
    __shared__ unsigned short As[128 * 32];
    __shared__ unsigned short Bs[128 * 32];

    const int tid  = threadIdx.x;
    const int lane = tid & 63;
    const int w    = tid >> 6;            // wave 0..3 (uniform per wave)
    const int wm   = (w >> 1) * 64;
    const int wn   = (w & 1) * 64;
    const int nblk = N >> 7;
    const int bm   = (int)(blockIdx.x / nblk) << 7;
    const int bn   = (int)(blockIdx.x % nblk) << 7;

    f32x4 acc[4][4] = {};

    const int srow = tid >> 2;
    const int scol = (tid & 3) << 3;
    const unsigned short* gA0 = A  + (size_t)(bm + srow) * K + scol;
    const unsigned short* gA1 = A  + (size_t)(bm + 64 + srow) * K + scol;
    const unsigned short* gB0 = Bm + (size_t)(bn + srow) * K + scol;
    const unsigned short* gB1 = Bm + (size_t)(bn + 64 + srow) * K + scol;

    unsigned short* ldsA0 = As + w * 512;
    unsigned short* ldsA1 = As + 2048 + w * 512;
    unsigned short* ldsB0 = Bs + w * 512;
    unsigned short* ldsB1 = Bs + 2048 + w * 512;

    const int frow = lane & 15;          // m (or n) within 16-tile
    const int fk   = (lane >> 4) << 3;   // k offset (quad*8)

    for (int kt = 0; kt < K; kt += 32) {
        __syncthreads();
        __builtin_amdgcn_global_load_lds((gptr_t)(gA0 + kt), (lptr_t)ldsA0, 16, 0, 0);
        __builtin_amdgcn_global_load_lds((gptr_t)(gA1 + kt), (lptr_t)ldsA1, 16, 0, 0);
        __builtin_amdgcn_global_load_lds((gptr_t)(gB0 + kt), (lptr_t)ldsB0, 16, 0, 0);
        __builtin_amdgcn_global_load_lds((gptr_t)(gB1 + kt), (lptr_t)ldsB1, 16, 0, 0);
        __syncthreads();

        bf16x8 af[4], bf[4];
#pragma unroll
        for (int mt = 0; mt < 4; ++mt)
            af[mt] = *(const bf16x8*)(As + (wm + mt * 16 + frow) * 32 + fk);
#pragma unroll
        for (int nt = 0; nt < 4; ++nt)
            bf[nt] = *(const bf16x8*)(Bs + (wn + nt * 16 + frow) * 32 + fk);
#pragma unroll
        for (int mt = 0; mt < 4; ++mt)
#pragma unroll
            for (int nt = 0; nt < 4; ++nt)
                acc[mt][nt] = __builtin_amdgcn_mfma_f32_16x16x32_bf16(
                    af[mt], bf[nt], acc[mt][nt], 0, 0, 0);
    }

    // epilogue: C/D layout col = lane&15, row = (lane>>4)*4 + reg  [m89-verified]
    const int c_col = lane & 15;
    const int c_row = (lane >> 4) << 2;
#pragma unroll
    for (int nt = 0; nt < 4; ++nt) {
        const int gn = bn + wn + nt * 16 + c_col;
        const float bv = bias[gn];
#pragma unroll
        for (int mt = 0; mt < 4; ++mt) {
            const int gm0 = bm + wm + mt * 16 + c_row;
#pragma unroll
            for (int r = 0; r < 4; ++r) {
                float v = acc[mt][nt][r] + bv;
                size_t idx = (size_t)(gm0 + r) * N + gn;
                if (STORE_BF16) ((unsigned short*)Cout)[idx] = f2bf(v);
                else            ((float*)Cout)[idx] = v;
            }
        }
    }
}

// ---------------------------------------------------------------- sequential scan
// 1 wave per batch element. Lane owns h[lane*8 .. lane*8+7] in registers.
// Critical path per step: s -> pre -> tanh -> partial dot -> DPP reduce -> s.
__global__ __launch_bounds__(64)
void scan_kernel(const unsigned short* __restrict__ xproj,  // (B,T,H) bf16
                 const float* __restrict__ h0,              // (B,H)
                 const float* __restrict__ U,               // (H,2)
                 const float* __restrict__ V,               // (H,2)
                 float* __restrict__ hall_f32,              // (B,T,H) -> d_out
                 unsigned short* __restrict__ hall_bf) {    // (B,T,H) -> ws
    const int b = blockIdx.x;
    const int lane = threadIdx.x;
    const int hbase = lane * 8;

    float h[8], V0[8], V1[8], U0[8], U1[8];
#pragma unroll
    for (int j = 0; j < 8; ++j) {
        h[j]  = h0[b * H_ + hbase + j];
        V0[j] = V[(hbase + j) * 2 + 0];
        V1[j] = V[(hbase + j) * 2 + 1];
        U0[j] = U[(hbase + j) * 2 + 0];
        U1[j] = U[(hbase + j) * 2 + 1];
    }

    const unsigned short* xp_ptr = xproj + (size_t)b * T_ * H_ + hbase;
    float* ho = hall_f32 + (size_t)b * T_ * H_ + hbase;
    unsigned short* hb = hall_bf + (size_t)b * T_ * H_ + hbase;

    const float inv_h = 1.0f / (float)H_;
    uint4 xcur = *(const uint4*)xp_ptr;

    // initial s = V^T h
    float s0 = 0.f, s1 = 0.f;
#pragma unroll
    for (int j = 0; j < 8; ++j) { s0 += h[j] * V0[j]; s1 += h[j] * V1[j]; }
    s0 = wave_sum64(s0);
    s1 = wave_sum64(s1);

    for (int t = 0; t < T_; ++t) {
        uint4 xnext = make_uint4(0u, 0u, 0u, 0u);
        if (t + 1 < T_) xnext = *(const uint4*)(xp_ptr + (size_t)(t + 1) * H_);

        // unpack xproj (bf16) for this step
        float xp[8];
        {
            unsigned int uu[4] = {xcur.x, xcur.y, xcur.z, xcur.w};
#pragma unroll
            for (int q = 0; q < 4; ++q) {
                xp[2 * q + 0] = bf2f((unsigned short)(uu[q] & 0xffffu));
                xp[2 * q + 1] = bf2f((unsigned short)(uu[q] >> 16));
            }
        }

        const float c0 = s0 * inv_h, c1 = s1 * inv_h;
        float g[8];
#pragma unroll
        for (int j = 0; j < 8; ++j)
            g[j] = fast_tanh(xp[j] + c0 * U0[j] + c1 * U1[j]);

        // h update (off critical path)
#pragma unroll
        for (int j = 0; j < 8; ++j)
            h[j] = 0.9f * h[j] + 0.1f * g[j];

        // s recurrence: s_{t+1} = 0.9*s_t + 0.1 * V^T g   (critical path)
        float p0a = 0.f, p0b = 0.f, p1a = 0.f, p1b = 0.f;
#pragma unroll
        for (int j = 0; j < 4; ++j) {
            p0a += g[j] * V0[j];       p0b += g[j + 4] * V0[j + 4];
            p1a += g[j] * V1[j];       p1b += g[j + 4] * V1[j + 4];
        }
        float r0 = wave_sum64(p0a + p0b);
        float r1 = wave_sum64(p1a + p1b);
        s0 = 0.9f * s0 + 0.1f * r0;
        s1 = 0.9f * s1 + 0.1f * r1;

        // stores (fire-and-forget)
        float4 v0 = make_float4(h[0], h[1], h[2], h[3]);
        float4 v1 = make_float4(h[4], h[5], h[6], h[7]);
        *(float4*)(ho + (size_t)t * H_ + 0) = v0;
        *(float4*)(ho + (size_t)t * H_ + 4) = v1;
        uint4 pb;
        pb.x = ((unsigned int)f2bf(h[1]) << 16) | f2bf(h[0]);
        pb.y = ((unsigned int)f2bf(h[3]) << 16) | f2bf(h[2]);
        pb.z = ((unsigned int)f2bf(h[5]) << 16) | f2bf(h[4]);
        pb.w = ((unsigned int)f2bf(h[7]) << 16) | f2bf(h[6]);
        *(uint4*)(hb + (size_t)t * H_) = pb;

        xcur = xnext;
    }
}

// ---------------------------------------------------------------- launch
extern "C" void kernel_launch(void* const* d_in, const int* in_sizes, int n_in,
                              void* d_out, int out_size, void* d_ws, size_t ws_size,
                              hipStream_t stream) {
    const float* x   = (const float*)d_in[0];
    const float* h0  = (const float*)d_in[1];
    const float* Wxh = (const float*)d_in[2];
    const float* bxh = (const float*)d_in[3];
    const float* U   = (const float*)d_in[4];
    const float* V   = (const float*)d_in[5];
    const float* Why = (const float*)d_in[6];
    const float* bhy = (const float*)d_in[7];

    float* y    = (float*)d_out;                    // (B,T,O)
    float* hall = y + (size_t)B_ * T_ * O_;         // (B,T,H)

    unsigned short* x_bf    = (unsigned short*)d_ws;                 // B*T*I
    unsigned short* Wxh_bf  = x_bf + (size_t)B_ * T_ * I_;           // H*I
    unsigned short* Why_bf  = Wxh_bf + (size_t)H_ * I_;              // O*H
    unsigned short* xp_bf   = Why_bf + (size_t)O_ * H_;              // B*T*H
    unsigned short* hall_bf = xp_bf + (size_t)B_ * T_ * H_;          // B*T*H

    cast_f32_bf16<<<(B_ * T_ * I_) / 1024, 256, 0, stream>>>(x, x_bf, B_ * T_ * I_);
    cast_f32_bf16<<<(H_ * I_) / 1024, 256, 0, stream>>>(Wxh, Wxh_bf, H_ * I_);
    cast_f32_bf16<<<(O_ * H_) / 1024, 256, 0, stream>>>(Why, Why_bf, O_ * H_);

    gemm_bt<true><<<dim3((B_ * T_ / 128) * (H_ / 128)), 256, 0, stream>>>(
        x_bf, Wxh_bf, bxh, xp_bf, B_ * T_, H_, I_);

    scan_kernel<<<B_, 64, 0, stream>>>(xp_bf, h0, U, V, hall, hall_bf);

    gemm_bt<false><<<dim3((B_ * T_ / 128) * (O_ / 128)), 256, 0, stream>>>(
        hall_bf, Why_bf, bhy, y, B_ * T_, O_, H_);
}